// Round 10
// baseline (126.423 us; speedup 1.0000x reference)
//
#include <hip/hip_runtime.h>
#include <hip/hip_bf16.h>

typedef __attribute__((ext_vector_type(4))) float f32x4;
typedef __attribute__((ext_vector_type(8))) short s16x8;
typedef __attribute__((ext_vector_type(4))) unsigned short u16x4;

__device__ __forceinline__ unsigned short f2bf(float f) {
  unsigned u = __builtin_bit_cast(unsigned, f);
  u += 0x7fffu + ((u >> 16) & 1u);
  return (unsigned short)(u >> 16);
}

// ---------------------------------------------------------------------------
// K1: mod[b][j] = silu(emb[b]) . ada_w[j] + ada_b[j]     (32 x 512), pure f32.
// ---------------------------------------------------------------------------
__global__ __launch_bounds__(512) void k_mod(const float* __restrict__ emb,
                                             const float* __restrict__ ada_w,
                                             const float* __restrict__ ada_b,
                                             float* __restrict__ mod) {
  __shared__ __align__(16) float semb[32][1028];  // silu(emb) f32, padded row (+4)
  const int t = threadIdx.x;
  for (int i = t; i < 8192; i += 512) {           // 8192 float4 = 32x1024
    f32x4 v = ((const f32x4*)emb)[i];
    f32x4 s;
#pragma unroll
    for (int j = 0; j < 4; ++j) s[j] = v[j] / (1.f + __expf(-v[j]));
    *(f32x4*)&semb[i >> 8][(i & 255) << 2] = s;
  }
  __syncthreads();
  const int jl = t >> 5, b = t & 31;
  const int j = blockIdx.x * 16 + jl;
  const f32x4* aw = (const f32x4*)(ada_w + (size_t)j * 1024);
  float acc = 0.f;
  for (int q = 0; q < 256; ++q) {
    f32x4 a = aw[q];
    f32x4 sv = *(const f32x4*)&semb[b][q * 4];
    acc += a[0] * sv[0] + a[1] * sv[1] + a[2] * sv[2] + a[3] * sv[3];
  }
  mod[b * 512 + j] = acc + ada_b[j];
}

// ---------------------------------------------------------------------------
// K2: W'[b][o][c] = conv_w[o][c]*(1+scale[b][c]) (bf16) in MFMA-frag staged
// layout (verified r2-r9). Also d[b][o] = sum_c conv_w[o][c]*shift[b][c]+conv_b.
// ---------------------------------------------------------------------------
__global__ __launch_bounds__(256) void k_prep(const float* __restrict__ mod,
                                              const float* __restrict__ conv_w,
                                              const float* __restrict__ conv_b,
                                              unsigned short* __restrict__ wp,
                                              float* __restrict__ dvec) {
  const int b = blockIdx.y;
  const int o = blockIdx.x * 4 + (threadIdx.x >> 6);
  const int l = threadIdx.x & 63;
  const float* sh = mod + b * 512;        // shift = first half
  const float* sc = mod + b * 512 + 256;  // scale = second half
  f32x4 cw = ((const f32x4*)(conv_w + (size_t)o * 256))[l];
  f32x4 s4 = ((const f32x4*)sc)[l];
  f32x4 h4 = ((const f32x4*)sh)[l];
  u16x4 wq;
#pragma unroll
  for (int j = 0; j < 4; ++j) wq[j] = f2bf(cw[j] * (1.f + s4[j]));
  const int wr = o >> 6, m = (o >> 4) & 3, lr = o & 15;
  const int kk = l >> 3, g = (l >> 1) & 3, jb = 4 * (l & 1);
  *(u16x4*)(wp + (size_t)b * 65536 + (((wr * 4 + m) * 8 + kk) * 512 + g * 128 + lr * 8 + jb)) = wq;
  float dd = cw[0] * h4[0] + cw[1] * h4[1] + cw[2] * h4[2] + cw[3] * h4[3];
#pragma unroll
  for (int off = 32; off; off >>= 1) dd += __shfl_down(dd, off);
  if (l == 0) dvec[b * 256 + o] = dd + conv_b[o];
}

// ---------------------------------------------------------------------------
// K3: fused rms + GEMM + selu. grid(16,32): block = (256-wide s-tile, b).
// 512 thr = 8 waves (4Mx2N). K in 8 chunks of 32 c, DMA'd f32 [c][s] into LDS
// (1 KB contiguous per instr), dbuf, counted vmcnt(4) + raw s_barrier (r9).
// NEW: LDS-bounce epilogue — deposit finalized 64ox256s sub-tiles into the
// (dead) staging buffer, then stream out with 1 KB-contiguous store instrs.
// Write granularity 64 B -> 1024 B; everything else identical to r9.
// ---------------------------------------------------------------------------
__global__ __launch_bounds__(512, 2) void k_main(const float* __restrict__ x,
                                                 const unsigned short* __restrict__ wp,
                                                 const float* __restrict__ dvec,
                                                 float* __restrict__ out) {
  constexpr int HW = 4096;
  // overlay: xf[2][32][256] f32 (65536 B) is dead after the GEMM loop;
  // epi[64][258] f32 (66048 B) reuses it. prt/rms live beyond both.
  __shared__ __align__(16) unsigned char smem[69120];
  float(*xf)[32][256] = (float(*)[32][256])smem;
  float(*epi)[258] = (float(*)[258])smem;
  float* prt = (float*)(smem + 66048);    // [2][256]
  float* rms = (float*)(smem + 68096);    // [256]

  const int t = threadIdx.x;
  const int b = blockIdx.y;
  const int s0 = blockIdx.x * 256;
  const int w = t >> 6, lane = t & 63;
  const int wr = w >> 1, wc = w & 1;      // wave grid 4(M) x 2(N): 64 o x 128 s
  const int lr = lane & 15, g = lane >> 4;

  const float* xb = x + (size_t)b * (256 * HW) + s0;
  const unsigned short* A2 = wp + (size_t)b * 65536;

  // DMA one K-chunk's rows for this wave: 4 rows x 1 KB, one instr per row.
#define ISSUE(K, BUF)                                                                     \
  {                                                                                       \
    _Pragma("unroll") for (int i = 0; i < 4; ++i) {                                       \
      const float* gp = xb + (size_t)((K)*32 + w * 4 + i) * HW + lane * 4;                \
      void* lp = (void*)&xf[BUF][w * 4 + i][0];                                           \
      __builtin_amdgcn_global_load_lds((const __attribute__((address_space(1))) void*)gp, \
                                       (__attribute__((address_space(3))) void*)lp, 16,   \
                                       0, 0);                                             \
    }                                                                                     \
  }

  ISSUE(0, 0);
  ISSUE(1, 1);

  const int sS = t & 255, ch = t >> 8;    // sumsq: 2 threads per s, 16 c each
  float rs = 0.f;
  f32x4 acc[4][8];
#pragma unroll
  for (int m = 0; m < 4; ++m)
#pragma unroll
    for (int n = 0; n < 8; ++n) acc[m][n] = f32x4{0.f, 0.f, 0.f, 0.f};

#pragma unroll
  for (int k = 0; k < 8; ++k) {
    const int buf = k & 1;
    if (k < 7) {
      asm volatile("s_waitcnt vmcnt(4)" ::: "memory");   // chunk k landed, k+1 in flight
    } else {
      asm volatile("s_waitcnt vmcnt(0)" ::: "memory");
    }
    __builtin_amdgcn_s_barrier();

    // sumsq slice for this chunk
#pragma unroll
    for (int i = 0; i < 16; ++i) {
      float v = xf[buf][ch * 16 + i][sS];
      rs += v * v;
    }

    // GEMM on chunk k
    s16x8 af[4];
#pragma unroll
    for (int m = 0; m < 4; ++m)
      af[m] = *(const s16x8*)(A2 + (((wr * 4 + m) * 8 + k) * 512 + lane * 8));
#pragma unroll
    for (int n = 0; n < 8; ++n) {
      const int s = 128 * wc + 16 * n + lr;
      s16x8 bf;
#pragma unroll
      for (int j = 0; j < 8; ++j) bf[j] = (short)f2bf(xf[buf][g * 8 + j][s]);
#pragma unroll
      for (int m = 0; m < 4; ++m)
        acc[m][n] = __builtin_amdgcn_mfma_f32_16x16x32_bf16(af[m], bf, acc[m][n], 0, 0, 0);
    }

    asm volatile("s_waitcnt lgkmcnt(0)" ::: "memory");   // my chunk-k LDS reads done
    __builtin_amdgcn_s_barrier();                        // all waves' reads done
    if (k < 6) ISSUE(k + 2, buf);                        // safe to overwrite buf
  }
#undef ISSUE

  // ---- rms ----
  prt[ch * 256 + sS] = rs;
  __syncthreads();
  if (t < 256) rms[t] = rsqrtf((prt[t] + prt[256 + t]) * (1.0f / 256.0f) + 1e-6f);
  __syncthreads();                        // rms ready; xf fully dead -> epi reuse OK

  // ---- epilogue: LDS-bounce for 1 KB-contiguous stores ----
  float rr[8];
#pragma unroll
  for (int n = 0; n < 8; ++n) rr[n] = rms[128 * wc + 16 * n + lr];
  const float* dvb = dvec + (size_t)b * 256;
  float* obase = out + (size_t)b * (256 * HW) + s0;

  for (int j = 0; j < 4; ++j) {           // wr-group j owns o-rows 64j..64j+63
    if (wr == j) {
#pragma unroll
      for (int m = 0; m < 4; ++m) {
        const int ro = 16 * m + 4 * g;
        const f32x4 dv = *(const f32x4*)(dvb + 64 * j + ro);
#pragma unroll
        for (int n = 0; n < 8; ++n) {
          const int s = 128 * wc + 16 * n + lr;
#pragma unroll
          for (int r = 0; r < 4; ++r) {
            float v = rr[n] * acc[m][n][r] + dv[r];
            epi[ro + r][s] = v > 0.f ? 1.0507009873554805f * v
                                     : 1.7580993408473766f * (__expf(v) - 1.f);
          }
        }
      }
    }
    __syncthreads();                      // deposit visible to all
    float* ob = obase + (size_t)(64 * j) * HW;
#pragma unroll
    for (int i = 0; i < 8; ++i) {         // each wave streams 8 full rows
      const int rl = w * 8 + i;
      f32x4 vv = *(const f32x4*)&epi[rl][4 * lane];
      *(f32x4*)(ob + (size_t)rl * HW + 4 * lane) = vv;  // 1 KB contiguous / instr
    }
    __syncthreads();                      // rows drained before next deposit
  }
}

// ---------------------------------------------------------------------------
extern "C" void kernel_launch(void* const* d_in, const int* in_sizes, int n_in,
                              void* d_out, int out_size, void* d_ws, size_t ws_size,
                              hipStream_t stream) {
  const float* x      = (const float*)d_in[0];
  const float* emb    = (const float*)d_in[1];
  const float* ada_w  = (const float*)d_in[2];
  const float* ada_b  = (const float*)d_in[3];
  const float* conv_w = (const float*)d_in[4];
  const float* conv_b = (const float*)d_in[5];
  float* out = (float*)d_out;

  float* mod  = (float*)d_ws;                               // 32*512 f32
  float* dvec = mod + 32 * 512;                             // 32*256 f32
  unsigned short* wp = (unsigned short*)(dvec + 32 * 256);  // 32*256*256 bf16 (staged layout)

  k_mod<<<dim3(32), 512, 0, stream>>>(emb, ada_w, ada_b, mod);
  k_prep<<<dim3(64, 32), 256, 0, stream>>>(mod, conv_w, conv_b, wp, dvec);
  k_main<<<dim3(16, 32), 512, 0, stream>>>(x, wp, dvec, out);
}

// Round 11
// 98.851 us; speedup vs baseline: 1.2789x; 1.2789x over previous
//
#include <hip/hip_runtime.h>
#include <hip/hip_bf16.h>

typedef __attribute__((ext_vector_type(4))) float f32x4;
typedef __attribute__((ext_vector_type(8))) short s16x8;
typedef __attribute__((ext_vector_type(4))) unsigned short u16x4;

__device__ __forceinline__ unsigned short f2bf(float f) {
  unsigned u = __builtin_bit_cast(unsigned, f);
  u += 0x7fffu + ((u >> 16) & 1u);
  return (unsigned short)(u >> 16);
}

// ---------------------------------------------------------------------------
// K1: mod[b][j] = silu(emb[b]) . ada_w[j] + ada_b[j]     (32 x 512), pure f32.
// ---------------------------------------------------------------------------
__global__ __launch_bounds__(512) void k_mod(const float* __restrict__ emb,
                                             const float* __restrict__ ada_w,
                                             const float* __restrict__ ada_b,
                                             float* __restrict__ mod) {
  __shared__ __align__(16) float semb[32][1028];  // silu(emb) f32, padded row (+4)
  const int t = threadIdx.x;
  for (int i = t; i < 8192; i += 512) {           // 8192 float4 = 32x1024
    f32x4 v = ((const f32x4*)emb)[i];
    f32x4 s;
#pragma unroll
    for (int j = 0; j < 4; ++j) s[j] = v[j] / (1.f + __expf(-v[j]));
    *(f32x4*)&semb[i >> 8][(i & 255) << 2] = s;
  }
  __syncthreads();
  const int jl = t >> 5, b = t & 31;
  const int j = blockIdx.x * 16 + jl;
  const f32x4* aw = (const f32x4*)(ada_w + (size_t)j * 1024);
  float acc = 0.f;
  for (int q = 0; q < 256; ++q) {
    f32x4 a = aw[q];
    f32x4 sv = *(const f32x4*)&semb[b][q * 4];
    acc += a[0] * sv[0] + a[1] * sv[1] + a[2] * sv[2] + a[3] * sv[3];
  }
  mod[b * 512 + j] = acc + ada_b[j];
}

// ---------------------------------------------------------------------------
// K2: W'[b][o][c] = conv_w[o][c]*(1+scale[b][c]) (bf16) in MFMA-frag staged
// layout (verified r2-r10). Also d[b][o] = sum_c conv_w[o][c]*shift[b][c]+conv_b.
// ---------------------------------------------------------------------------
__global__ __launch_bounds__(256) void k_prep(const float* __restrict__ mod,
                                              const float* __restrict__ conv_w,
                                              const float* __restrict__ conv_b,
                                              unsigned short* __restrict__ wp,
                                              float* __restrict__ dvec) {
  const int b = blockIdx.y;
  const int o = blockIdx.x * 4 + (threadIdx.x >> 6);
  const int l = threadIdx.x & 63;
  const float* sh = mod + b * 512;        // shift = first half
  const float* sc = mod + b * 512 + 256;  // scale = second half
  f32x4 cw = ((const f32x4*)(conv_w + (size_t)o * 256))[l];
  f32x4 s4 = ((const f32x4*)sc)[l];
  f32x4 h4 = ((const f32x4*)sh)[l];
  u16x4 wq;
#pragma unroll
  for (int j = 0; j < 4; ++j) wq[j] = f2bf(cw[j] * (1.f + s4[j]));
  const int wr = o >> 6, m = (o >> 4) & 3, lr = o & 15;
  const int kk = l >> 3, g = (l >> 1) & 3, jb = 4 * (l & 1);
  *(u16x4*)(wp + (size_t)b * 65536 + (((wr * 4 + m) * 8 + kk) * 512 + g * 128 + lr * 8 + jb)) = wq;
  float dd = cw[0] * h4[0] + cw[1] * h4[1] + cw[2] * h4[2] + cw[3] * h4[3];
#pragma unroll
  for (int off = 32; off; off >>= 1) dd += __shfl_down(dd, off);
  if (l == 0) dvec[b * 256 + o] = dd + conv_b[o];
}

// ---------------------------------------------------------------------------
// K3: fused rms + GEMM + selu. grid(16,32): block = (256-wide s-tile, b).
// 512 thr = 8 waves (4Mx2N). K in 8 chunks of 32 c, DMA'd f32 [c][s] into LDS
// (1 KB/instr), dbuf, counted vmcnt(4) (r9 schedule). NEW vs r9: per-chunk
// CONVERT pass -> bf16 bt[s][c] tile (swizzle vs=(s>>4)&3 on c-bits 3-4);
// GEMM B-frags become 8 ds_read_b128/wave/chunk (was 64 scalar reads + 64
// cvt, 4x redundant). Sumsq folded into convert. prt/rms overlay dead bt.
// LDS = 80 KB exactly -> 2 blocks/CU. Epilogue = r9 direct stores.
// ---------------------------------------------------------------------------
__global__ __launch_bounds__(512, 2) void k_main(const float* __restrict__ x,
                                                 const unsigned short* __restrict__ wp,
                                                 const float* __restrict__ dvec,
                                                 float* __restrict__ out) {
  constexpr int HW = 4096;
  __shared__ __align__(16) unsigned char smem[81920];
  float(*xf)[32][256] = (float(*)[32][256])smem;                      // [2][32][256] f32, 64 KB
  unsigned char* bt = smem + 65536;                                   // [256][32] bf16, 16 KB
  float* prt = (float*)(smem + 65536);                                // overlay after loop [256]
  float* rms = (float*)(smem + 65536 + 1024);                         // [256]

  const int t = threadIdx.x;
  const int b = blockIdx.y;
  const int s0 = blockIdx.x * 256;
  const int w = t >> 6, lane = t & 63;
  const int wr = w >> 1, wc = w & 1;      // wave grid 4(M) x 2(N): 64 o x 128 s
  const int lr = lane & 15, g = lane >> 4;

  const float* xb = x + (size_t)b * (256 * HW) + s0;
  const unsigned short* A2 = wp + (size_t)b * 65536;

  // DMA one K-chunk's rows for this wave: 4 rows x 1 KB, one instr per row.
#define ISSUE(K, BUF)                                                                     \
  {                                                                                       \
    _Pragma("unroll") for (int i = 0; i < 4; ++i) {                                       \
      const float* gp = xb + (size_t)((K)*32 + w * 4 + i) * HW + lane * 4;                \
      void* lp = (void*)&xf[BUF][w * 4 + i][0];                                           \
      __builtin_amdgcn_global_load_lds((const __attribute__((address_space(1))) void*)gp, \
                                       (__attribute__((address_space(3))) void*)lp, 16,   \
                                       0, 0);                                             \
    }                                                                                     \
  }

  ISSUE(0, 0);
  ISSUE(1, 1);

  // convert-pass mapping: this thread owns c in {4cg..4cg+3}, s in {4sl..4sl+3}
  const int cg = lane >> 3;               // 0..7
  const int sl = 8 * w + (lane & 7);      // 0..63
  f32x4 ssq = {0.f, 0.f, 0.f, 0.f};       // sumsq partial for s=4sl..4sl+3

  f32x4 acc[4][8];
#pragma unroll
  for (int m = 0; m < 4; ++m)
#pragma unroll
    for (int n = 0; n < 8; ++n) acc[m][n] = f32x4{0.f, 0.f, 0.f, 0.f};

#pragma unroll
  for (int k = 0; k < 8; ++k) {
    const int buf = k & 1;
    if (k < 7) {
      asm volatile("s_waitcnt vmcnt(4)" ::: "memory");   // chunk k landed, k+1 in flight
    } else {
      asm volatile("s_waitcnt vmcnt(0)" ::: "memory");
    }
    asm volatile("s_waitcnt lgkmcnt(0)" ::: "memory");   // my bt reads (GEMM k-1) done
    __builtin_amdgcn_s_barrier();

    // ---- CONVERT: xf[buf] -> bt, fold sumsq ----
    f32x4 vv[4];
#pragma unroll
    for (int dc = 0; dc < 4; ++dc) vv[dc] = *(const f32x4*)&xf[buf][4 * cg + dc][4 * sl];
#pragma unroll
    for (int dc = 0; dc < 4; ++dc) ssq += vv[dc] * vv[dc];
#pragma unroll
    for (int si = 0; si < 4; ++si) {
      const int s = 4 * sl + si;
      const int vs = (s >> 4) & 3;
      u16x4 pk = {f2bf(vv[0][si]), f2bf(vv[1][si]), f2bf(vv[2][si]), f2bf(vv[3][si])};
      *(u16x4*)(bt + s * 64 + ((cg ^ (2 * vs)) << 3)) = pk;
    }
    asm volatile("s_waitcnt lgkmcnt(0)" ::: "memory");   // my bt writes + xf reads done
    __builtin_amdgcn_s_barrier();                        // bt ready; xf[buf] free

    // ---- GEMM on chunk k: A from L2 staged wp, B via ds_read_b128 ----
    s16x8 af[4];
#pragma unroll
    for (int m = 0; m < 4; ++m)
      af[m] = *(const s16x8*)(A2 + (((wr * 4 + m) * 8 + k) * 512 + lane * 8));
#pragma unroll
    for (int n = 0; n < 8; ++n) {
      const int s = 128 * wc + 16 * n + lr;
      const int vs = n & 3;               // == (s>>4)&3
      s16x8 bf = *(const s16x8*)(bt + s * 64 + ((g ^ vs) << 4));
#pragma unroll
      for (int m = 0; m < 4; ++m)
        acc[m][n] = __builtin_amdgcn_mfma_f32_16x16x32_bf16(af[m], bf, acc[m][n], 0, 0, 0);
    }
    if (k < 6) ISSUE(k + 2, buf);
  }
#undef ISSUE

  // ---- rms: reduce ssq across cg groups (lane bits 3..5), overlay prt on bt ----
  asm volatile("s_waitcnt lgkmcnt(0)" ::: "memory");
  __syncthreads();                        // all bt reads retired -> overlay safe
#pragma unroll
  for (int off = 8; off <= 32; off <<= 1) {
#pragma unroll
    for (int j = 0; j < 4; ++j) ssq[j] += __shfl_xor(ssq[j], off);
  }
  if (lane < 8) *(f32x4*)&prt[4 * (8 * w + lane)] = ssq;
  __syncthreads();
  if (t < 256) rms[t] = rsqrtf(prt[t] * (1.0f / 256.0f) + 1e-6f);
  __syncthreads();

  // ---- epilogue: y = rms*G + d; selu (r9 direct stores) ----
  float rr[8];
#pragma unroll
  for (int n = 0; n < 8; ++n) rr[n] = rms[128 * wc + 16 * n + lr];
  float* ob = out + (size_t)b * (256 * HW) + s0;
#pragma unroll
  for (int m = 0; m < 4; ++m) {
    const int o0 = 64 * wr + 16 * m + 4 * g;
    const f32x4 dv = *(const f32x4*)(dvec + (size_t)b * 256 + o0);
#pragma unroll
    for (int n = 0; n < 8; ++n) {
#pragma unroll
      for (int r = 0; r < 4; ++r) {
        float v = rr[n] * acc[m][n][r] + dv[r];
        float res = v > 0.f ? 1.0507009873554805f * v
                            : 1.7580993408473766f * (__expf(v) - 1.f);
        ob[(size_t)(o0 + r) * HW + 128 * wc + 16 * n + lr] = res;
      }
    }
  }
}

// ---------------------------------------------------------------------------
extern "C" void kernel_launch(void* const* d_in, const int* in_sizes, int n_in,
                              void* d_out, int out_size, void* d_ws, size_t ws_size,
                              hipStream_t stream) {
  const float* x      = (const float*)d_in[0];
  const float* emb    = (const float*)d_in[1];
  const float* ada_w  = (const float*)d_in[2];
  const float* ada_b  = (const float*)d_in[3];
  const float* conv_w = (const float*)d_in[4];
  const float* conv_b = (const float*)d_in[5];
  float* out = (float*)d_out;

  float* mod  = (float*)d_ws;                               // 32*512 f32
  float* dvec = mod + 32 * 512;                             // 32*256 f32
  unsigned short* wp = (unsigned short*)(dvec + 32 * 256);  // 32*256*256 bf16 (staged layout)

  k_mod<<<dim3(32), 512, 0, stream>>>(emb, ada_w, ada_b, mod);
  k_prep<<<dim3(64, 32), 256, 0, stream>>>(mod, conv_w, conv_b, wp, dvec);
  k_main<<<dim3(16, 32), 512, 0, stream>>>(x, wp, dvec, out);
}

// Round 12
// 98.321 us; speedup vs baseline: 1.2858x; 1.0054x over previous
//
#include <hip/hip_runtime.h>
#include <hip/hip_bf16.h>

typedef __attribute__((ext_vector_type(4))) float f32x4;
typedef __attribute__((ext_vector_type(8))) short s16x8;
typedef __attribute__((ext_vector_type(4))) unsigned short u16x4;

__device__ __forceinline__ unsigned short f2bf(float f) {
  unsigned u = __builtin_bit_cast(unsigned, f);
  u += 0x7fffu + ((u >> 16) & 1u);
  return (unsigned short)(u >> 16);
}

// ---------------------------------------------------------------------------
// K1: mod[b][j] = silu(emb[b]) . ada_w[j] + ada_b[j]  (32 x 512).
// grid(32,32): block = (16-j group, b). silu computed once per block (1024
// elems), ada_w rows read exactly once device-wide.
// ---------------------------------------------------------------------------
__global__ __launch_bounds__(512) void k_mod(const float* __restrict__ emb,
                                             const float* __restrict__ ada_w,
                                             const float* __restrict__ ada_b,
                                             float* __restrict__ mod) {
  __shared__ __align__(16) float se[1024];
  const int t = threadIdx.x;
  const int b = blockIdx.y;
  if (t < 256) {
    f32x4 v = ((const f32x4*)(emb + (size_t)b * 1024))[t];
    f32x4 s;
#pragma unroll
    for (int j = 0; j < 4; ++j) s[j] = v[j] / (1.f + __expf(-v[j]));
    *(f32x4*)&se[4 * t] = s;
  }
  __syncthreads();
  const int jl = t >> 5, l32 = t & 31;
  const int j = blockIdx.x * 16 + jl;
  const f32x4* aw = (const f32x4*)(ada_w + (size_t)j * 1024);
  float acc = 0.f;
#pragma unroll
  for (int i = 0; i < 8; ++i) {
    const int q = l32 + 32 * i;
    f32x4 a = aw[q];
    f32x4 sv = *(const f32x4*)&se[4 * q];
    acc += a[0] * sv[0] + a[1] * sv[1] + a[2] * sv[2] + a[3] * sv[3];
  }
#pragma unroll
  for (int off = 1; off <= 16; off <<= 1) acc += __shfl_xor(acc, off);
  if (l32 == 0) mod[b * 512 + j] = acc + ada_b[j];
}

// ---------------------------------------------------------------------------
// K2: W'[b][o][c] = conv_w[o][c]*(1+scale[b][c]) (bf16) in MFMA-frag staged
// layout (verified r2-r11). Also d[b][o] = sum_c conv_w[o][c]*shift[b][c]+conv_b.
// ---------------------------------------------------------------------------
__global__ __launch_bounds__(256) void k_prep(const float* __restrict__ mod,
                                              const float* __restrict__ conv_w,
                                              const float* __restrict__ conv_b,
                                              unsigned short* __restrict__ wp,
                                              float* __restrict__ dvec) {
  const int b = blockIdx.y;
  const int o = blockIdx.x * 4 + (threadIdx.x >> 6);
  const int l = threadIdx.x & 63;
  const float* sh = mod + b * 512;        // shift = first half
  const float* sc = mod + b * 512 + 256;  // scale = second half
  f32x4 cw = ((const f32x4*)(conv_w + (size_t)o * 256))[l];
  f32x4 s4 = ((const f32x4*)sc)[l];
  f32x4 h4 = ((const f32x4*)sh)[l];
  u16x4 wq;
#pragma unroll
  for (int j = 0; j < 4; ++j) wq[j] = f2bf(cw[j] * (1.f + s4[j]));
  const int wr = o >> 6, m = (o >> 4) & 3, lr = o & 15;
  const int kk = l >> 3, g = (l >> 1) & 3, jb = 4 * (l & 1);
  *(u16x4*)(wp + (size_t)b * 65536 + (((wr * 4 + m) * 8 + kk) * 512 + g * 128 + lr * 8 + jb)) = wq;
  float dd = cw[0] * h4[0] + cw[1] * h4[1] + cw[2] * h4[2] + cw[3] * h4[3];
#pragma unroll
  for (int off = 32; off; off >>= 1) dd += __shfl_down(dd, off);
  if (l == 0) dvec[b * 256 + o] = dd + conv_b[o];
}

// ---------------------------------------------------------------------------
// K3: fused rms + GEMM + selu. grid(16,32), 512 thr = 8 waves (4Mx2N).
// Loop (r11, verified): K in 8 chunks of 32c DMA'd f32 [c][s] (1 KB/instr),
// dbuf, vmcnt(4); convert pass -> swizzled bf16 bt; GEMM via ds_read_b128.
// NEW: bounce epilogue — per 64-o band: owning waves deposit selu'd tile
// into epi[64][260] (overlay on dead xf), raw s_barrier + lgkmcnt-only waits
// (stores NEVER waited on), all 8 waves drain with 1 KB-contiguous
// global_store_dwordx4. Write granularity 64 B -> 1 KB without r10's
// store-retire serialization. LDS 81920 -> 2 blocks/CU.
// ---------------------------------------------------------------------------
__global__ __launch_bounds__(512, 2) void k_main(const float* __restrict__ x,
                                                 const unsigned short* __restrict__ wp,
                                                 const float* __restrict__ dvec,
                                                 float* __restrict__ out) {
  constexpr int HW = 4096;
  __shared__ __align__(16) unsigned char smem[81920];
  float(*xf)[32][256] = (float(*)[32][256])smem;   // [2][32][256] f32, 64 KB
  unsigned char* bt = smem + 65536;                // [256][32] bf16, 16 KB
  float* epi = (float*)smem;                       // overlay post-loop: [64][260]
  float* prt = (float*)(smem + 79872);             // overlay on bt tail [256]
  float* rms = (float*)(smem + 80896);             // [256]

  const int t = threadIdx.x;
  const int b = blockIdx.y;
  const int s0 = blockIdx.x * 256;
  const int w = t >> 6, lane = t & 63;
  const int wr = w >> 1, wc = w & 1;      // wave grid 4(M) x 2(N): 64 o x 128 s
  const int lr = lane & 15, g = lane >> 4;

  const float* xb = x + (size_t)b * (256 * HW) + s0;
  const unsigned short* A2 = wp + (size_t)b * 65536;

#define ISSUE(K, BUF)                                                                     \
  {                                                                                       \
    _Pragma("unroll") for (int i = 0; i < 4; ++i) {                                       \
      const float* gp = xb + (size_t)((K)*32 + w * 4 + i) * HW + lane * 4;                \
      void* lp = (void*)&xf[BUF][w * 4 + i][0];                                           \
      __builtin_amdgcn_global_load_lds((const __attribute__((address_space(1))) void*)gp, \
                                       (__attribute__((address_space(3))) void*)lp, 16,   \
                                       0, 0);                                             \
    }                                                                                     \
  }

  ISSUE(0, 0);
  ISSUE(1, 1);

  const int cg = lane >> 3;               // c-quad 0..7
  const int sl = 8 * w + (lane & 7);      // s-quad 0..63
  f32x4 ssq = {0.f, 0.f, 0.f, 0.f};

  f32x4 acc[4][8];
#pragma unroll
  for (int m = 0; m < 4; ++m)
#pragma unroll
    for (int n = 0; n < 8; ++n) acc[m][n] = f32x4{0.f, 0.f, 0.f, 0.f};

#pragma unroll
  for (int k = 0; k < 8; ++k) {
    const int buf = k & 1;
    if (k < 7) {
      asm volatile("s_waitcnt vmcnt(4)" ::: "memory");
    } else {
      asm volatile("s_waitcnt vmcnt(0)" ::: "memory");
    }
    asm volatile("s_waitcnt lgkmcnt(0)" ::: "memory");
    __builtin_amdgcn_s_barrier();

    // ---- CONVERT: xf[buf] -> bt, fold sumsq ----
    f32x4 vv[4];
#pragma unroll
    for (int dc = 0; dc < 4; ++dc) vv[dc] = *(const f32x4*)&xf[buf][4 * cg + dc][4 * sl];
#pragma unroll
    for (int dc = 0; dc < 4; ++dc) ssq += vv[dc] * vv[dc];
#pragma unroll
    for (int si = 0; si < 4; ++si) {
      const int s = 4 * sl + si;
      const int vs = (s >> 4) & 3;
      u16x4 pk = {f2bf(vv[0][si]), f2bf(vv[1][si]), f2bf(vv[2][si]), f2bf(vv[3][si])};
      *(u16x4*)(bt + s * 64 + ((cg ^ (2 * vs)) << 3)) = pk;
    }
    asm volatile("s_waitcnt lgkmcnt(0)" ::: "memory");
    __builtin_amdgcn_s_barrier();

    // ---- GEMM on chunk k ----
    s16x8 af[4];
#pragma unroll
    for (int m = 0; m < 4; ++m)
      af[m] = *(const s16x8*)(A2 + (((wr * 4 + m) * 8 + k) * 512 + lane * 8));
#pragma unroll
    for (int n = 0; n < 8; ++n) {
      const int s = 128 * wc + 16 * n + lr;
      const int vs = n & 3;
      s16x8 bf = *(const s16x8*)(bt + s * 64 + ((g ^ vs) << 4));
#pragma unroll
      for (int m = 0; m < 4; ++m)
        acc[m][n] = __builtin_amdgcn_mfma_f32_16x16x32_bf16(af[m], bf, acc[m][n], 0, 0, 0);
    }
    if (k < 6) ISSUE(k + 2, buf);
  }
#undef ISSUE

  // ---- rms (prt/rms overlay bt tail; bt fully dead after loop) ----
  asm volatile("s_waitcnt lgkmcnt(0)" ::: "memory");
  __syncthreads();
#pragma unroll
  for (int off = 8; off <= 32; off <<= 1) {
#pragma unroll
    for (int j = 0; j < 4; ++j) ssq[j] += __shfl_xor(ssq[j], off);
  }
  if (lane < 8) *(f32x4*)&prt[4 * (8 * w + lane)] = ssq;
  __syncthreads();
  if (t < 256) rms[t] = rsqrtf(prt[t] * (1.0f / 256.0f) + 1e-6f);
  __syncthreads();

  // ---- bounce epilogue: per band, deposit -> barrier -> 1 KB-row drain ----
  float rr[8];
#pragma unroll
  for (int n = 0; n < 8; ++n) rr[n] = rms[128 * wc + 16 * n + lr];
  const float* dvb = dvec + (size_t)b * 256;
  float* obase = out + (size_t)b * (256 * HW) + s0;

  for (int j = 0; j < 4; ++j) {
    if (wr == j) {
#pragma unroll
      for (int m = 0; m < 4; ++m) {
        const int ro = 16 * m + 4 * g;
        const f32x4 dv = *(const f32x4*)(dvb + 64 * j + ro);
#pragma unroll
        for (int n = 0; n < 8; ++n) {
          const int s = 128 * wc + 16 * n + lr;
#pragma unroll
          for (int r = 0; r < 4; ++r) {
            float v = rr[n] * acc[m][n][r] + dv[r];
            epi[(ro + r) * 260 + s] = v > 0.f ? 1.0507009873554805f * v
                                              : 1.7580993408473766f * (__expf(v) - 1.f);
          }
        }
      }
    }
    asm volatile("s_waitcnt lgkmcnt(0)" ::: "memory");  // deposits visible
    __builtin_amdgcn_s_barrier();
    float* ob = obase + (size_t)(64 * j) * HW;
#pragma unroll
    for (int i = 0; i < 8; ++i) {          // each wave drains 8 full rows
      const int rl = w * 8 + i;
      f32x4 vv = *(const f32x4*)&epi[rl * 260 + 4 * lane];
      *(f32x4*)(ob + (size_t)rl * HW + 4 * lane) = vv;  // 1 KB contiguous
    }
    asm volatile("s_waitcnt lgkmcnt(0)" ::: "memory");  // drain READS done only
    __builtin_amdgcn_s_barrier();                       // (stores never waited)
  }
}

// ---------------------------------------------------------------------------
extern "C" void kernel_launch(void* const* d_in, const int* in_sizes, int n_in,
                              void* d_out, int out_size, void* d_ws, size_t ws_size,
                              hipStream_t stream) {
  const float* x      = (const float*)d_in[0];
  const float* emb    = (const float*)d_in[1];
  const float* ada_w  = (const float*)d_in[2];
  const float* ada_b  = (const float*)d_in[3];
  const float* conv_w = (const float*)d_in[4];
  const float* conv_b = (const float*)d_in[5];
  float* out = (float*)d_out;

  float* mod  = (float*)d_ws;                               // 32*512 f32
  float* dvec = mod + 32 * 512;                             // 32*256 f32
  unsigned short* wp = (unsigned short*)(dvec + 32 * 256);  // 32*256*256 bf16 (staged layout)

  k_mod<<<dim3(32, 32), 512, 0, stream>>>(emb, ada_w, ada_b, mod);
  k_prep<<<dim3(64, 32), 256, 0, stream>>>(mod, conv_w, conv_b, wp, dvec);
  k_main<<<dim3(16, 32), 512, 0, stream>>>(x, wp, dvec, out);
}